// Round 5
// baseline (338.157 us; speedup 1.0000x reference)
//
#include <hip/hip_runtime.h>
#include <stdint.h>

#define NCOLS 8192
#define BS    256
#define NB    16
#define NT    32                 // cols per tile
#define STRIP 256                // cols per wg
#define NTILES (STRIP / NT)      // 8
#define GX    (NCOLS / STRIP)    // 32

typedef float    f32x4  __attribute__((ext_vector_type(4)));
typedef short    bf16x8 __attribute__((ext_vector_type(8)));
typedef unsigned u32x4  __attribute__((ext_vector_type(4)));

// RNE-pack two fp32 into one dword of two bf16 (lo = first arg)
__device__ __forceinline__ unsigned pack2(float lo, float hi) {
  unsigned a = __builtin_bit_cast(unsigned, lo);
  unsigned b = __builtin_bit_cast(unsigned, hi);
  a += 0x7FFFu + ((a >> 16) & 1u);
  b += 0x7FFFu + ((b >> 16) & 1u);
  return (a >> 16) | (b & 0xFFFF0000u);
}

// Convert W (16x256x256 fp32) -> bf16 in ws. 8 elems/thread.
__global__ __launch_bounds__(256) void wcvt_kernel(const float* __restrict__ Wf,
                                                   unsigned* __restrict__ Wb) {
  int i = blockIdx.x * 256 + threadIdx.x;
  f32x4 a = ((const f32x4*)Wf)[2 * i];
  f32x4 c = ((const f32x4*)Wf)[2 * i + 1];
  u32x4 o;
  o.x = pack2(a.x, a.y); o.y = pack2(a.z, a.w);
  o.z = pack2(c.x, c.y); o.w = pack2(c.z, c.w);
  ((u32x4*)Wb)[i] = o;
}

// Streaming wg: block b x STRIP=256 cols, 8 tiles of NT=32.
// Round-2 stage mechanics (reg-load X -> pack2 once -> bf16 XOR-swizzled LDS,
// conflict-free ds_read_b128 frags) inside round-3 streaming structure
// (loads for t+1 issued before compute of t; pack consumes them at tile end
// with a counted vmcnt; one raw s_barrier per tile; stores drift).
template<bool USE_WS>
__global__ __launch_bounds__(256, 3)
void bg_kernel(const float* __restrict__ X, const float* __restrict__ Wf,
               const unsigned short* __restrict__ Wb, float* __restrict__ out) {
  __shared__ unsigned xs[2][NT * 128];  // two 16 KiB bf16 [n][kd] swizzled buffers
  __shared__ float    es[4 * 16 * 36];  // 9 KiB epilogue transpose scratch

  const int b     = blockIdx.y;
  const int cbase = blockIdx.x * STRIP;
  const int tid   = threadIdx.x;
  const int wid   = tid >> 6;
  const int lane  = tid & 63;
  const int cg    = lane & 7;    // col group: 8 x f32x4 = 32 floats/row
  const int sub   = lane >> 3;   // 8 row-subgroups
  const int ln16  = lane & 15;
  const int quad  = lane >> 4;

  const float* xb0 = X + (size_t)b * BS * NCOLS + cbase + 4 * cg;

  f32x4 st[8];  // 32 VGPR staging, held across one tile's compute
  auto stage_load = [&](int t) {
    const float* xb = xb0 + t * NT;
#pragma unroll
    for (int p = 0; p < 4; ++p) {
      const int k0 = wid * 64 + p * 16 + sub * 2;  // wave owns a 64-row K band
      st[2 * p]     = *(const f32x4*)(xb + (size_t)k0 * NCOLS);
      st[2 * p + 1] = *(const f32x4*)(xb + (size_t)(k0 + 1) * NCOLS);
    }
  };
  auto stage_pack = [&](unsigned* buf) {
#pragma unroll
    for (int p = 0; p < 4; ++p) {
      const int kd = wid * 32 + p * 8 + sub;
#pragma unroll
      for (int j = 0; j < 4; ++j) {
        const int n = 4 * cg + j;
        const int f = (n ^ (n >> 2)) & 7;
        buf[n * 128 + (kd ^ (f << 2))] = pack2(st[2 * p][j], st[2 * p + 1][j]);
      }
    }
  };

  const size_t wbase = ((size_t)(b * BS + wid * 64 + ln16)) * BS + quad * 8;
  auto loadA = [&](int ks, int mt) -> bf16x8 {
    const size_t off = wbase + (size_t)(mt * 16) * BS + ks * 32;
    if (USE_WS) {
      return *(const bf16x8*)(Wb + off);
    } else {
      f32x4 w0 = *(const f32x4*)(Wf + off);
      f32x4 w1 = *(const f32x4*)(Wf + off + 4);
      union { unsigned u[4]; bf16x8 v; } cv;
      cv.u[0] = pack2(w0.x, w0.y); cv.u[1] = pack2(w0.z, w0.w);
      cv.u[2] = pack2(w1.x, w1.y); cv.u[3] = pack2(w1.z, w1.w);
      return cv.v;
    }
  };

  // ---- prologue: tile 0 through the normal stage path, full sync once
  stage_load(0);
  __builtin_amdgcn_sched_barrier(0);
  stage_pack(xs[0]);
  __syncthreads();

  unsigned* cur = xs[0];
  unsigned* nxt = xs[1];

#pragma unroll 1
  for (int t = 0; t < NTILES; ++t) {
    if (t + 1 < NTILES) {
      stage_load(t + 1);                  // 8 dwordx4: in flight across tile t
      __builtin_amdgcn_sched_barrier(0);  // pin issue before compute
    }

    auto loadB = [&](int ks, int nt) -> bf16x8 {
      const int n = nt * 16 + ln16;
      const int f = (n ^ (n >> 2)) & 7;
      return *(const bf16x8*)(&cur[n * 128 + ((ks * 16 + quad * 4) ^ (f << 2))]);
    };

    // ---- compute tile t: 2-deep fragment pipeline, b128 LDS reads
    f32x4 acc[4][2] = {};
    bf16x8 afr[2][4], bfr[2][2];
#pragma unroll
    for (int i = 0; i < 4; ++i) afr[0][i] = loadA(0, i);
#pragma unroll
    for (int i = 0; i < 2; ++i) bfr[0][i] = loadB(0, i);

#pragma unroll
    for (int ks = 0; ks < 8; ++ks) {
      const int curp = ks & 1, nxtp = curp ^ 1;
      if (ks < 7) {
#pragma unroll
        for (int i = 0; i < 4; ++i) afr[nxtp][i] = loadA(ks + 1, i);
#pragma unroll
        for (int i = 0; i < 2; ++i) bfr[nxtp][i] = loadB(ks + 1, i);
      }
#pragma unroll
      for (int mt = 0; mt < 4; ++mt)
#pragma unroll
        for (int nt = 0; nt < 2; ++nt)
          acc[mt][nt] = __builtin_amdgcn_mfma_f32_16x16x32_bf16(afr[curp][mt], bfr[curp][nt],
                                                                acc[mt][nt], 0, 0, 0);
    }

    // ---- epilogue: per-wave private LDS transpose -> 8 f32x4 stores
    {
      const int c0 = cbase + t * NT;
      float* lw = es + wid * 576;  // 16 rows x 36 floats
      const int erow  = lane >> 3;
      const int ecol  = 4 * (lane & 7);
#pragma unroll
      for (int mt = 0; mt < 4; ++mt) {
#pragma unroll
        for (int r = 0; r < 4; ++r)
#pragma unroll
          for (int nt = 0; nt < 2; ++nt)
            lw[(quad * 4 + r) * 36 + nt * 16 + ln16] = acc[mt][nt][r];
        __asm__ volatile("s_waitcnt lgkmcnt(0)" ::: "memory");
#pragma unroll
        for (int j = 0; j < 2; ++j) {
          f32x4 v = *(const f32x4*)(lw + (j * 8 + erow) * 36 + ecol);
          *(f32x4*)(out + (size_t)(b * BS + wid * 64 + mt * 16 + j * 8 + erow) * NCOLS
                        + c0 + ecol) = v;
        }
        __asm__ volatile("s_waitcnt lgkmcnt(0)" ::: "memory");
      }
    }

    if (t + 1 < NTILES) {
      __builtin_amdgcn_sched_barrier(0);
      stage_pack(nxt);  // consumes st: compiler emits counted vmcnt (stores drift)
      __asm__ volatile("s_waitcnt lgkmcnt(0)" ::: "memory");
      __builtin_amdgcn_s_barrier();
      __builtin_amdgcn_sched_barrier(0);
      unsigned* tmp = cur; cur = nxt; nxt = tmp;
    }
  }
}

extern "C" void kernel_launch(void* const* d_in, const int* in_sizes, int n_in,
                              void* d_out, int out_size, void* d_ws, size_t ws_size,
                              hipStream_t stream) {
  const float* X  = (const float*)d_in[0];
  const float* Wf = (const float*)d_in[1];
  float* out      = (float*)d_out;
  dim3 grid(GX, NB);
  const size_t wneed = (size_t)NB * BS * BS * sizeof(unsigned short);
  if (ws_size >= wneed) {
    unsigned* Wb = (unsigned*)d_ws;
    wcvt_kernel<<<dim3((NB * BS * BS) / (256 * 8)), 256, 0, stream>>>(Wf, Wb);
    bg_kernel<true><<<grid, 256, 0, stream>>>(X, Wf, (const unsigned short*)Wb, out);
  } else {
    bg_kernel<false><<<grid, 256, 0, stream>>>(X, Wf, nullptr, out);
  }
}

// Round 6
// 264.959 us; speedup vs baseline: 1.2763x; 1.2763x over previous
//
#include <hip/hip_runtime.h>
#include <stdint.h>

#define NCOLS 8192
#define BS    256
#define NB    16
#define NT    32                 // cols per tile
#define STRIP 256                // cols per wg
#define NTILES (STRIP / NT)      // 8
#define GX    (NCOLS / STRIP)    // 32

typedef float    f32x4  __attribute__((ext_vector_type(4)));
typedef short    bf16x8 __attribute__((ext_vector_type(8)));
typedef unsigned u32x4  __attribute__((ext_vector_type(4)));

// RNE-pack two fp32 into one dword of two bf16 (lo = first arg)
__device__ __forceinline__ unsigned pack2(float lo, float hi) {
  unsigned a = __builtin_bit_cast(unsigned, lo);
  unsigned b = __builtin_bit_cast(unsigned, hi);
  a += 0x7FFFu + ((a >> 16) & 1u);
  b += 0x7FFFu + ((b >> 16) & 1u);
  return (a >> 16) | (b & 0xFFFF0000u);
}

// Convert W (16x256x256 fp32) -> bf16 in ws. 8 elems/thread.
__global__ __launch_bounds__(256) void wcvt_kernel(const float* __restrict__ Wf,
                                                   unsigned* __restrict__ Wb) {
  int i = blockIdx.x * 256 + threadIdx.x;
  f32x4 a = ((const f32x4*)Wf)[2 * i];
  f32x4 c = ((const f32x4*)Wf)[2 * i + 1];
  u32x4 o;
  o.x = pack2(a.x, a.y); o.y = pack2(a.z, a.w);
  o.z = pack2(c.x, c.y); o.w = pack2(c.z, c.w);
  ((u32x4*)Wb)[i] = o;
}

// 512-thread streaming wg: block b x STRIP=256 cols, 8 tiles of NT=32.
// Each of 8 waves owns M=32 rows; W band = wfr[8][2] = 64 VGPR, loaded once.
// X staged by global_load_lds into xf (fp32, source-XOR-permuted so the pack
// pass reads conflict-free b128), cooperatively packed to bf16 XOR-swizzled xb,
// computed via conflict-free ds_read_b128 frags. Counted vmcnt(4) per tile;
// loads for t+1 in flight across all of tile t's compute+epilogue.
template<bool USE_WS>
__global__ __launch_bounds__(512, 4)
void bg_kernel(const float* __restrict__ X, const float* __restrict__ Wf,
               const unsigned short* __restrict__ Wb, float* __restrict__ out) {
  __shared__ float    xf[8192];   // 32 KiB fp32 staging (permuted cols)
  __shared__ unsigned xb[4096];   // 16 KiB bf16 [n][kd] XOR-swizzled
  __shared__ float    es[4096];   // 16 KiB: 8 waves x 16x32 swizzled epilogue

  const int b     = blockIdx.y;
  const int cbase = blockIdx.x * STRIP;
  const int tid   = threadIdx.x;
  const int w     = tid >> 6;       // wave 0..7
  const int lane  = tid & 63;
  const int ln16  = lane & 15;
  const int quad  = lane >> 4;      // 0..3
  const int rowl  = lane >> 3;      // 0..7
  const int jjl   = lane & 7;       // 0..7

  // ---- stage: 4 x global_load_lds(16B)/lane; wave w stages K-rows w*32..+31.
  // Source col is XOR-permuted by g(k)=(k>>1)&7 so pack reads are conflict-free.
  auto stage = [&](int t) {
    const float* srcb = X + (size_t)(b * BS) * NCOLS + cbase + t * NT;
#pragma unroll
    for (int p = 0; p < 4; ++p) {
      const int k   = w * 32 + p * 8 + rowl;
      const int g   = (p * 4 + (rowl >> 1)) & 7;   // == (k>>1)&7
      const int col = 4 * (jjl ^ g);
      __builtin_amdgcn_global_load_lds(
          (const __attribute__((address_space(1))) void*)(srcb + (size_t)k * NCOLS + col),
          (__attribute__((address_space(3))) void*)(xf + w * 1024 + p * 256),
          16, 0, 0);
    }
  };

  // ---- pack: xf -> xb. Lane handles kd = w*16 + p*8 + rowl (g(2kd)=rowl),
  // reads 2 conflict-free b128 rows, writes 8 swizzled dwords (<=2-way).
  auto pack_tile = [&]() {
#pragma unroll
    for (int p = 0; p < 2; ++p) {
      const int kd = w * 16 + p * 8 + rowl;
      const int k0 = 2 * kd;
      const float* r0 = xf + k0 * 32 + 4 * (jjl ^ rowl);
      f32x4 lo = *(const f32x4*)r0;
      f32x4 hi = *(const f32x4*)(r0 + 32);
#pragma unroll
      for (int j = 0; j < 4; ++j) {
        const int n = 4 * jjl + j;
        const int f = (n ^ (n >> 2)) & 7;
        xb[n * 128 + (kd ^ (f << 2))] = pack2(lo[j], hi[j]);
      }
    }
  };

  // ---- W band into registers: wave w owns M-rows w*32..+31 -> wfr[8][2], 64 VGPR
  bf16x8 wfr[8][2];
  {
    const size_t wb0 = ((size_t)(b * BS + w * 32 + ln16)) * BS + quad * 8;
    if (USE_WS) {
#pragma unroll
      for (int ks = 0; ks < 8; ++ks)
#pragma unroll
        for (int mt = 0; mt < 2; ++mt)
          wfr[ks][mt] = *(const bf16x8*)(Wb + wb0 + (size_t)(mt * 16) * BS + ks * 32);
    } else {
#pragma unroll
      for (int ks = 0; ks < 8; ++ks)
#pragma unroll
        for (int mt = 0; mt < 2; ++mt) {
          const size_t off = wb0 + (size_t)(mt * 16) * BS + ks * 32;
          f32x4 w0 = *(const f32x4*)(Wf + off);
          f32x4 w1 = *(const f32x4*)(Wf + off + 4);
          union { unsigned u[4]; bf16x8 v; } cv;
          cv.u[0] = pack2(w0.x, w0.y); cv.u[1] = pack2(w0.z, w0.w);
          cv.u[2] = pack2(w1.x, w1.y); cv.u[3] = pack2(w1.z, w1.w);
          wfr[ks][mt] = cv.v;
        }
    }
  }

  // ---- prologue: tile 0 staged + W in regs; single full drain; pack; publish
  stage(0);
  __builtin_amdgcn_sched_barrier(0);
  __asm__ volatile("s_waitcnt vmcnt(0)" ::: "memory");
  pack_tile();
  __asm__ volatile("s_waitcnt lgkmcnt(0)" ::: "memory");
  __builtin_amdgcn_s_barrier();
  __builtin_amdgcn_sched_barrier(0);

#pragma unroll 1
  for (int t = 0; t < NTILES; ++t) {
    if (t + 1 < NTILES) {
      stage(t + 1);                       // 4 loads: oldest vmem ops this tile
      __builtin_amdgcn_sched_barrier(0);
    }

    // ---- compute tile t from xb: zero global deps, 2-deep LDS frag pipeline
    auto loadB = [&](int ks, int nt) -> bf16x8 {
      const int n = nt * 16 + ln16;
      const int f = (n ^ (n >> 2)) & 7;
      return *(const bf16x8*)(&xb[n * 128 + ((ks * 16 + quad * 4) ^ (f << 2))]);
    };

    f32x4 acc[2][2] = {};
    bf16x8 bfr[2][2];
#pragma unroll
    for (int i = 0; i < 2; ++i) bfr[0][i] = loadB(0, i);
#pragma unroll
    for (int ks = 0; ks < 8; ++ks) {
      const int curp = ks & 1, nxtp = curp ^ 1;
      if (ks < 7) {
#pragma unroll
        for (int i = 0; i < 2; ++i) bfr[nxtp][i] = loadB(ks + 1, i);
      }
#pragma unroll
      for (int mt = 0; mt < 2; ++mt)
#pragma unroll
        for (int nt = 0; nt < 2; ++nt)
          acc[mt][nt] = __builtin_amdgcn_mfma_f32_16x16x32_bf16(wfr[ks][mt], bfr[curp][nt],
                                                                acc[mt][nt], 0, 0, 0);
    }

    // ---- epilogue: per-wave 16x32 swizzled transpose in es -> f32x4 stores
    {
      const int c0 = cbase + t * NT;
      float* lw = es + w * 512;
#pragma unroll
      for (int mt = 0; mt < 2; ++mt) {
#pragma unroll
        for (int r = 0; r < 4; ++r) {
          const int row16 = quad * 4 + r;
          const int sx    = 4 * (row16 & 7);
#pragma unroll
          for (int nt = 0; nt < 2; ++nt)
            lw[row16 * 32 + ((nt * 16 + ln16) ^ sx)] = acc[mt][nt][r];
        }
        __asm__ volatile("s_waitcnt lgkmcnt(0)" ::: "memory");
#pragma unroll
        for (int j = 0; j < 2; ++j) {
          const int rr = j * 8 + rowl;
          f32x4 v = *(const f32x4*)(lw + rr * 32 + ((4 * jjl) ^ (4 * (rr & 7))));
          *(f32x4*)(out + (size_t)(b * BS + w * 32 + mt * 16 + rr) * NCOLS
                        + c0 + 4 * jjl) = v;
        }
        __asm__ volatile("s_waitcnt lgkmcnt(0)" ::: "memory");
      }
    }

    if (t + 1 < NTILES) {
      __builtin_amdgcn_sched_barrier(0);
      // outstanding (FIFO): 4 stage loads (oldest) + 4 epilogue stores.
      // vmcnt(4): loads complete, stores stay in flight. Never 0 in-loop.
      __asm__ volatile("s_waitcnt vmcnt(4)" ::: "memory");
      __builtin_amdgcn_s_barrier();       // all waves done reading xb
      __builtin_amdgcn_sched_barrier(0);
      pack_tile();                        // xf(t+1) -> xb (own-wave rows)
      __asm__ volatile("s_waitcnt lgkmcnt(0)" ::: "memory");
      __builtin_amdgcn_s_barrier();       // xb published
      __builtin_amdgcn_sched_barrier(0);
    }
  }
}

extern "C" void kernel_launch(void* const* d_in, const int* in_sizes, int n_in,
                              void* d_out, int out_size, void* d_ws, size_t ws_size,
                              hipStream_t stream) {
  const float* X  = (const float*)d_in[0];
  const float* Wf = (const float*)d_in[1];
  float* out      = (float*)d_out;
  dim3 grid(GX, NB);
  const size_t wneed = (size_t)NB * BS * BS * sizeof(unsigned short);
  if (ws_size >= wneed) {
    unsigned* Wb = (unsigned*)d_ws;
    wcvt_kernel<<<dim3((NB * BS * BS) / (256 * 8)), 256, 0, stream>>>(Wf, Wb);
    bg_kernel<true><<<grid, 512, 0, stream>>>(X, Wf, (const unsigned short*)Wb, out);
  } else {
    bg_kernel<false><<<grid, 512, 0, stream>>>(X, Wf, nullptr, out);
  }
}

// Round 7
// 252.741 us; speedup vs baseline: 1.3380x; 1.0483x over previous
//
#include <hip/hip_runtime.h>
#include <stdint.h>

#define NCOLS 8192
#define BS    256
#define NB    16
#define NT    64                  // cols per tile
#define NTILES 8
#define STRIP (NT * NTILES)       // 512 cols per wg
#define GX    (NCOLS / STRIP)     // 16 -> grid 16x16 = 256 wgs = 1/CU
#define NCW   8                   // consumer waves (M=32 each)
#define NPW   4                   // producer waves (64 K-rows each)

typedef float    f32x4  __attribute__((ext_vector_type(4)));
typedef short    bf16x8 __attribute__((ext_vector_type(8)));
typedef unsigned u32x4  __attribute__((ext_vector_type(4)));

// RNE-pack two fp32 into one dword of two bf16 (lo = first arg)
__device__ __forceinline__ unsigned pack2(float lo, float hi) {
  unsigned a = __builtin_bit_cast(unsigned, lo);
  unsigned b = __builtin_bit_cast(unsigned, hi);
  a += 0x7FFFu + ((a >> 16) & 1u);
  b += 0x7FFFu + ((b >> 16) & 1u);
  return (a >> 16) | (b & 0xFFFF0000u);
}

// Convert W (16x256x256 fp32) -> bf16 in ws. 8 elems/thread.
__global__ __launch_bounds__(256) void wcvt_kernel(const float* __restrict__ Wf,
                                                   unsigned* __restrict__ Wb) {
  int i = blockIdx.x * 256 + threadIdx.x;
  f32x4 a = ((const f32x4*)Wf)[2 * i];
  f32x4 c = ((const f32x4*)Wf)[2 * i + 1];
  u32x4 o;
  o.x = pack2(a.x, a.y); o.y = pack2(a.z, a.w);
  o.z = pack2(c.x, c.y); o.w = pack2(c.z, c.w);
  ((u32x4*)Wb)[i] = o;
}

// Producer/consumer wg: 12 waves, block b x STRIP=512 cols, 8 tiles of NT=64.
// 8 consumer waves: W band in regs (pinned), frags from swizzled bf16 xb,
// direct scalar-dword stores (no LDS epilogue). 4 producer waves: X fp32 ->
// regs -> pack2 -> b128 LDS writes, depth-2 prefetch (pack t+1 / load t+2).
// One raw s_barrier per tile; no vmcnt(0) drains in the loop on any path.
template<bool USE_WS>
__global__ __launch_bounds__(768, 3)
void bg_kernel(const float* __restrict__ X, const float* __restrict__ Wf,
               const unsigned short* __restrict__ Wb, float* __restrict__ out) {
  __shared__ unsigned xb[2][NT * 128];  // [n][kd^swz] dwords; 32 KiB per buffer

  const int b    = blockIdx.y;
  const int c0   = blockIdx.x * STRIP;
  const int tid  = threadIdx.x;
  const int wid  = tid >> 6;
  const int lane = tid & 63;

  if (wid < NCW) {
    // ================= CONSUMER =================
    const int cw   = wid;          // M-band cw*32..+31
    const int ln16 = lane & 15;
    const int quad = lane >> 4;

    // W band -> wfr[8][2] (64 VGPR), loaded once, pinned against remat.
    bf16x8 wfr[8][2];
    {
      const size_t wb0 = ((size_t)(b * BS + cw * 32 + ln16)) * BS + quad * 8;
      if (USE_WS) {
#pragma unroll
        for (int ks = 0; ks < 8; ++ks)
#pragma unroll
          for (int mt = 0; mt < 2; ++mt)
            wfr[ks][mt] = *(const bf16x8*)(Wb + wb0 + (size_t)(mt * 16) * BS + ks * 32);
      } else {
#pragma unroll
        for (int ks = 0; ks < 8; ++ks)
#pragma unroll
          for (int mt = 0; mt < 2; ++mt) {
            const size_t off = wb0 + (size_t)(mt * 16) * BS + ks * 32;
            f32x4 w0 = *(const f32x4*)(Wf + off);
            f32x4 w1 = *(const f32x4*)(Wf + off + 4);
            union { unsigned u[4]; bf16x8 v; } cv;
            cv.u[0] = pack2(w0.x, w0.y); cv.u[1] = pack2(w0.z, w0.w);
            cv.u[2] = pack2(w1.x, w1.y); cv.u[3] = pack2(w1.z, w1.w);
            wfr[ks][mt] = cv.v;
          }
      }
#pragma unroll
      for (int ks = 0; ks < 8; ++ks)
#pragma unroll
        for (int mt = 0; mt < 2; ++mt)
          __asm__ volatile("" : "+v"(wfr[ks][mt]));  // opaque: no remat possible
    }

    __builtin_amdgcn_s_barrier();  // tile 0 published by producers

#pragma unroll 1
    for (int t = 0; t < NTILES; ++t) {
      const unsigned* buf = &xb[t & 1][0];
      auto loadB = [&](int ks, int nt) -> bf16x8 {
        const int n = nt * 16 + ln16;
        const int f = (n ^ (n >> 2)) & 7;
        return *(const bf16x8*)(&buf[n * 128 + ((ks * 16 + quad * 4) ^ (f << 2))]);
      };

      f32x4 acc[2][4] = {};
      bf16x8 bfr[2][4];
#pragma unroll
      for (int i = 0; i < 4; ++i) bfr[0][i] = loadB(0, i);
#pragma unroll
      for (int ks = 0; ks < 8; ++ks) {
        const int curp = ks & 1, nxtp = curp ^ 1;
        if (ks < 7) {
#pragma unroll
          for (int i = 0; i < 4; ++i) bfr[nxtp][i] = loadB(ks + 1, i);
        }
#pragma unroll
        for (int mt = 0; mt < 2; ++mt)
#pragma unroll
          for (int nt = 0; nt < 4; ++nt)
            acc[mt][nt] = __builtin_amdgcn_mfma_f32_16x16x32_bf16(wfr[ks][mt], bfr[curp][nt],
                                                                  acc[mt][nt], 0, 0, 0);
      }

      // direct stores: C layout col=ln16, row=quad*4+r. 64B segments; nt pairs
      // complete 128B lines in L2. Stores drift (no in-loop waits on them).
      {
        const int cbt = c0 + t * NT;
#pragma unroll
        for (int mt = 0; mt < 2; ++mt)
#pragma unroll
          for (int r = 0; r < 4; ++r) {
            float* orow = out + (size_t)(b * BS + cw * 32 + mt * 16 + quad * 4 + r) * NCOLS
                              + cbt + ln16;
#pragma unroll
            for (int nt = 0; nt < 4; ++nt)
              orow[nt * 16] = acc[mt][nt][r];
          }
      }
      __builtin_amdgcn_s_barrier();  // ds_reads all consumed by MFMAs above
    }
  } else {
    // ================= PRODUCER =================
    const int pw = wid - NCW;      // K-band pw*64..+63
    const int lr = lane >> 3;      // 0..7 : 8-row group
    const int lc = lane & 7;       // 0..7 : 8-col group

    f32x4 st[16];  // held only across own pack; producers run no MFMA
    auto load_tile = [&](int t) {
      const float* base = X + ((size_t)(b * BS + pw * 64 + lr * 8)) * NCOLS
                            + c0 + t * NT + lc * 8;
#pragma unroll
      for (int u = 0; u < 8; ++u)
#pragma unroll
        for (int pp = 0; pp < 2; ++pp)
          st[u * 2 + pp] = *(const f32x4*)(base + (size_t)u * NCOLS + pp * 4);
    };
    // xb[n][kd^ (f<<2)]: kd0 = pw*32+lr*4 is 4-aligned and f<<2 only touches
    // bits>=2, so the 4 packed dwords stay contiguous -> b128 writes.
    auto pack_tile = [&](unsigned* buf) {
      const int kd0 = pw * 32 + lr * 4;
#pragma unroll
      for (int pp = 0; pp < 2; ++pp)
#pragma unroll
        for (int j = 0; j < 4; ++j) {
          const int n = lc * 8 + pp * 4 + j;
          const int f = (n ^ (n >> 2)) & 7;
          u32x4 o;
#pragma unroll
          for (int v = 0; v < 4; ++v)
            o[v] = pack2(st[(2 * v) * 2 + pp][j], st[(2 * v + 1) * 2 + pp][j]);
          *(u32x4*)(&buf[n * 128 + (kd0 ^ (f << 2))]) = o;
        }
    };

    // prologue: tile0 -> xb[0]; tile1 loads in flight; publish
    load_tile(0);
    pack_tile(xb[0]);              // compiler waits (counted) on st only
    load_tile(1);
    __builtin_amdgcn_sched_barrier(0);
    __asm__ volatile("s_waitcnt lgkmcnt(0)" ::: "memory");
    __builtin_amdgcn_s_barrier();

#pragma unroll 1
    for (int t = 0; t < NTILES; ++t) {
      if (t + 1 < NTILES) {
        pack_tile(&xb[(t + 1) & 1][0]);   // st = tile t+1, loaded a period ago
        if (t + 2 < NTILES) load_tile(t + 2);
        __builtin_amdgcn_sched_barrier(0);
        __asm__ volatile("s_waitcnt lgkmcnt(0)" ::: "memory");
      }
      __builtin_amdgcn_s_barrier();
    }
  }
}

extern "C" void kernel_launch(void* const* d_in, const int* in_sizes, int n_in,
                              void* d_out, int out_size, void* d_ws, size_t ws_size,
                              hipStream_t stream) {
  const float* X  = (const float*)d_in[0];
  const float* Wf = (const float*)d_in[1];
  float* out      = (float*)d_out;
  dim3 grid(GX, NB);
  const size_t wneed = (size_t)NB * BS * BS * sizeof(unsigned short);
  if (ws_size >= wneed) {
    unsigned* Wb = (unsigned*)d_ws;
    wcvt_kernel<<<dim3((NB * BS * BS) / (256 * 8)), 256, 0, stream>>>(Wf, Wb);
    bg_kernel<true><<<grid, 768, 0, stream>>>(X, Wf, (const unsigned short*)Wb, out);
  } else {
    bg_kernel<false><<<grid, 768, 0, stream>>>(X, Wf, nullptr, out);
  }
}